// Round 3
// baseline (210.132 us; speedup 1.0000x reference)
//
#include <hip/hip_runtime.h>
#include <hip/hip_bf16.h>

// ---- constants for this problem ----
// N=8192 tokens, DIM=1024, H=16, HKV=4, HD=64, B=8, S=1024

typedef __bf16 bf16x8 __attribute__((ext_vector_type(8)));
typedef float f32x4 __attribute__((ext_vector_type(4)));

__device__ __forceinline__ void async16(const void* g, void* l) {
  __builtin_amdgcn_global_load_lds((const __attribute__((address_space(1))) void*)g,
                                   (__attribute__((address_space(3))) void*)l, 16, 0, 0);
}

__device__ __forceinline__ unsigned short f2bfu(float x) {
  __hip_bfloat16 h = __float2bfloat16(x);
  return __builtin_bit_cast(unsigned short, h);
}

// ---------------- all input casts in one kernel ----------------
// regions (float4 units): x 2097152 | Wq 262144 | Wk 65536 | Wv 65536 | Wp 262144
__global__ __launch_bounds__(256) void castall(
    const float4* __restrict__ x, const float4* __restrict__ Wq,
    const float4* __restrict__ Wk, const float4* __restrict__ Wv,
    const float4* __restrict__ Wp,
    ushort4* __restrict__ xb, ushort4* __restrict__ w1b, ushort4* __restrict__ wpb) {
  int i = blockIdx.x * 256 + threadIdx.x;  // total 2752512
  const float4* src;
  ushort4* dst;
  if (i < 2097152)      { src = x + i;             dst = xb + i; }
  else if (i < 2359296) { src = Wq + (i - 2097152); dst = w1b + (i - 2097152); }
  else if (i < 2424832) { src = Wk + (i - 2359296); dst = w1b + (i - 2097152); }
  else if (i < 2490368) { src = Wv + (i - 2424832); dst = w1b + (i - 2097152); }
  else                  { src = Wp + (i - 2490368); dst = wpb + (i - 2490368); }
  float4 v = *src;
  ushort4 o;
  o.x = f2bfu(v.x); o.y = f2bfu(v.y); o.z = f2bfu(v.z); o.w = f2bfu(v.w);
  *dst = o;
}

// ---------------- fused QKV GEMM + RMSNorm + RoPE + gain -> bf16 q/k/v ----------------
// v3: T3-lite pipeline — double-buffered LDS, STAGE(t+1) issued BEFORE compute(t),
// ONE barrier per K-iter (the __syncthreads vmcnt(0) drain now lands after the
// ds_read+MFMA block has covered the load latency, instead of serializing it).
// LDS 64KB -> 2 blocks/CU. Keeps: BK=64, T2 XOR swizzle (pre-swizzled global
// source + swizzled read), T1 bijective XCD remap, Q pre-scale by 0.125*log2e.
__global__ __launch_bounds__(256, 2) void gemm_qkv(
    const __hip_bfloat16* __restrict__ A,   // [8192][1024] bf16
    const __hip_bfloat16* __restrict__ Bm,  // [1536][1024] bf16
    const float* __restrict__ cosb, const float* __restrict__ sinb,
    const float* __restrict__ qgain, const float* __restrict__ qscale,
    const float* __restrict__ kscale,
    __hip_bfloat16* __restrict__ Qo,  // [8192][16][64]
    __hip_bfloat16* __restrict__ Ko,  // [8192][4][64]
    __hip_bfloat16* __restrict__ Vo)  // [8192][4][64]
{
  __shared__ __align__(16) unsigned short As[2][128 * 64];
  __shared__ __align__(16) unsigned short Bs[2][128 * 64];
  const int tid = threadIdx.x;
  const int wave = tid >> 6, lane = tid & 63;
  const int quad = lane >> 4, l15 = lane & 15;
  // T1: bijective XCD swizzle (768 % 8 == 0)
  const int flat = blockIdx.x;
  const int swz = (flat & 7) * 96 + (flat >> 3);
  const int bn = swz % 12, bm = swz / 12;
  const int wm = (wave >> 1) * 64, wn = (wave & 1) * 64;
  // staging: chunk = 8 rows x 64 cols; dest LDS linear, source col pre-swizzled
  const int srow = lane >> 3;                    // row within chunk (== row&7)
  const int scol = ((lane & 7) ^ srow) * 8;      // inverse-swizzled global col
  const int K = 1024;

  f32x4 acc[4][4] = {};

  const __hip_bfloat16* Ab = A + (size_t)bm * 128 * K;
  const __hip_bfloat16* Bb = Bm + (size_t)bn * 128 * K;

  auto stage = [&](int t, int buf) {
#pragma unroll
    for (int c = 0; c < 4; c++) {
      const int ch = wave * 4 + c;               // 16 chunks cover 128 rows
      async16(Ab + (size_t)(ch * 8 + srow) * K + t * 64 + scol, &As[buf][ch * 512]);
      async16(Bb + (size_t)(ch * 8 + srow) * K + t * 64 + scol, &Bs[buf][ch * 512]);
    }
  };

  stage(0, 0);
  __syncthreads();                               // drains vmcnt(0): buf0 ready

  for (int t = 0; t < 16; t++) {
    const int cur = t & 1;
    if (t + 1 < 16) stage(t + 1, cur ^ 1);       // overlap: issue before compute
#pragma unroll
    for (int ks = 0; ks < 2; ks++) {
      bf16x8 af[4], bfr[4];
#pragma unroll
      for (int mt = 0; mt < 4; mt++) {
        const int row = wm + mt * 16 + l15;
        af[mt] = *(const bf16x8*)&As[cur][row * 64 + (((ks << 2) + quad) ^ (row & 7)) * 8];
      }
#pragma unroll
      for (int nt = 0; nt < 4; nt++) {
        const int row = wn + nt * 16 + l15;
        bfr[nt] = *(const bf16x8*)&Bs[cur][row * 64 + (((ks << 2) + quad) ^ (row & 7)) * 8];
      }
#pragma unroll
      for (int mt = 0; mt < 4; mt++)
#pragma unroll
        for (int nt = 0; nt < 4; nt++)
          acc[mt][nt] = __builtin_amdgcn_mfma_f32_16x16x32_bf16(af[mt], bfr[nt], acc[mt][nt], 0, 0, 0);
    }
    __syncthreads();                             // one barrier/iter: next buf ready
  }

  // ---- fused epilogue ----
  const int hg = bn * 2 + (wn >> 6);        // global output head 0..23
  const int tokbase = bm * 128 + wm;        // wave's first token

  if (hg >= 20) {
    // V head: plain bf16 store
    const int hv = hg - 20;
#pragma unroll
    for (int mt = 0; mt < 4; mt++)
#pragma unroll
      for (int r = 0; r < 4; r++) {
        const int tok = tokbase + mt * 16 + quad * 4 + r;
#pragma unroll
        for (int nt = 0; nt < 4; nt++)
          Vo[(size_t)tok * 256 + hv * 64 + nt * 16 + l15] = __float2bfloat16(acc[mt][nt][r]);
      }
  } else {
    const bool isq = hg < 16;
    const float scale = isq ? qscale[0] : kscale[0];
    // rope/gain/softmax-scale are all linear -> fold gain AND 0.125*log2e into inv (Q only)
    const float gain = isq ? qgain[hg] * 0.18033688011112042f : 1.0f;
    const float sg = scale * gain;
#pragma unroll
    for (int mt = 0; mt < 4; mt++) {
      float inv[4];
#pragma unroll
      for (int r = 0; r < 4; r++) {
        float ss = acc[mt][0][r] * acc[mt][0][r] + acc[mt][1][r] * acc[mt][1][r] +
                   acc[mt][2][r] * acc[mt][2][r] + acc[mt][3][r] * acc[mt][3][r];
#pragma unroll
        for (int off = 1; off < 16; off <<= 1) ss += __shfl_xor(ss, off);
        inv[r] = rsqrtf(ss * (1.0f / 64.0f) + 1.1920929e-07f) * sg;
      }
#pragma unroll
      for (int r = 0; r < 4; r++) {
        const int tok = tokbase + mt * 16 + quad * 4 + r;
        const float c0 = cosb[tok * 32 + l15], c1 = cosb[tok * 32 + 16 + l15];
        const float s0 = sinb[tok * 32 + l15], s1 = sinb[tok * 32 + 16 + l15];
        const float v0 = acc[mt][0][r] * inv[r];
        const float v1 = acc[mt][1][r] * inv[r];
        const float v2 = acc[mt][2][r] * inv[r];
        const float v3 = acc[mt][3][r] * inv[r];
        const float o0 = v0 * c0 + v2 * s0;
        const float o1 = v1 * c1 + v3 * s1;
        const float o2 = -v0 * s0 + v2 * c0;
        const float o3 = -v1 * s1 + v3 * c1;
        __hip_bfloat16* base = isq ? (Qo + (size_t)tok * 1024 + hg * 64)
                                   : (Ko + (size_t)tok * 256 + (hg - 16) * 64);
        base[l15]      = __float2bfloat16(o0);
        base[16 + l15] = __float2bfloat16(o1);
        base[32 + l15] = __float2bfloat16(o2);
        base[48 + l15] = __float2bfloat16(o3);
      }
    }
  }
}

// ---------------- proj GEMM: out = y @ Wp^T, 128x128, BK=64, same pipelined structure ----------------
__global__ __launch_bounds__(256, 2) void gemm_p(
    const __hip_bfloat16* __restrict__ A,   // [8192][1024] bf16
    const __hip_bfloat16* __restrict__ Bm,  // [1024][1024] bf16
    float* __restrict__ C)                  // [8192][1024] f32
{
  __shared__ __align__(16) unsigned short As[2][128 * 64];
  __shared__ __align__(16) unsigned short Bs[2][128 * 64];
  const int tid = threadIdx.x;
  const int wave = tid >> 6, lane = tid & 63;
  const int quad = lane >> 4, l15 = lane & 15;
  // T1: bijective XCD swizzle (512 % 8 == 0)
  const int flat = blockIdx.x;
  const int swz = (flat & 7) * 64 + (flat >> 3);
  const int bn = swz & 7, bm = swz >> 3;
  const int wm = (wave >> 1) * 64, wn = (wave & 1) * 64;
  const int srow = lane >> 3;
  const int scol = ((lane & 7) ^ srow) * 8;
  const int K = 1024;

  f32x4 acc[4][4] = {};

  const __hip_bfloat16* Ab = A + (size_t)bm * 128 * K;
  const __hip_bfloat16* Bb = Bm + (size_t)bn * 128 * K;

  auto stage = [&](int t, int buf) {
#pragma unroll
    for (int c = 0; c < 4; c++) {
      const int ch = wave * 4 + c;
      async16(Ab + (size_t)(ch * 8 + srow) * K + t * 64 + scol, &As[buf][ch * 512]);
      async16(Bb + (size_t)(ch * 8 + srow) * K + t * 64 + scol, &Bs[buf][ch * 512]);
    }
  };

  stage(0, 0);
  __syncthreads();

  for (int t = 0; t < 16; t++) {
    const int cur = t & 1;
    if (t + 1 < 16) stage(t + 1, cur ^ 1);
#pragma unroll
    for (int ks = 0; ks < 2; ks++) {
      bf16x8 af[4], bfr[4];
#pragma unroll
      for (int mt = 0; mt < 4; mt++) {
        const int row = wm + mt * 16 + l15;
        af[mt] = *(const bf16x8*)&As[cur][row * 64 + (((ks << 2) + quad) ^ (row & 7)) * 8];
      }
#pragma unroll
      for (int nt = 0; nt < 4; nt++) {
        const int row = wn + nt * 16 + l15;
        bfr[nt] = *(const bf16x8*)&Bs[cur][row * 64 + (((ks << 2) + quad) ^ (row & 7)) * 8];
      }
#pragma unroll
      for (int mt = 0; mt < 4; mt++)
#pragma unroll
        for (int nt = 0; nt < 4; nt++)
          acc[mt][nt] = __builtin_amdgcn_mfma_f32_16x16x32_bf16(af[mt], bfr[nt], acc[mt][nt], 0, 0, 0);
    }
    __syncthreads();
  }

#pragma unroll
  for (int mt = 0; mt < 4; mt++)
#pragma unroll
    for (int r = 0; r < 4; r++) {
      const int row = bm * 128 + wm + mt * 16 + quad * 4 + r;
#pragma unroll
      for (int nt = 0; nt < 4; nt++)
        C[(size_t)row * 1024 + bn * 128 + wn + nt * 16 + l15] = acc[mt][nt][r];
    }
}

// ---------------- transpose V (bf16 in) into Vt[b][kvh][d][s] ----------------
__global__ __launch_bounds__(256) void vtrans(const unsigned short* __restrict__ vkb,
                                              unsigned short* __restrict__ Vt) {
  __shared__ unsigned short t[64][65];
  const int st = blockIdx.x, kvh = blockIdx.y, b = blockIdx.z;
  const int tid = threadIdx.x;
  const int s0 = st * 64;
#pragma unroll
  for (int i = 0; i < 16; i++) {
    const int idx = tid + i * 256;
    const int sl = idx >> 6, d = idx & 63;
    t[sl][d] = vkb[(size_t)(b * 1024 + s0 + sl) * 256 + kvh * 64 + d];
  }
  __syncthreads();
#pragma unroll
  for (int i = 0; i < 16; i++) {
    const int idx = tid + i * 256;
    const int d = idx >> 6, sl = idx & 63;
    Vt[((size_t)(b * 4 + kvh) * 64 + d) * 1024 + s0 + sl] = t[sl][d];
  }
}

// ---------------- flash attention v4 (unchanged) ----------------
__global__ __launch_bounds__(256, 2) void attn(
    const __hip_bfloat16* __restrict__ Q,   // [N][16][64] (pre-scaled)
    const __hip_bfloat16* __restrict__ Kk,  // [N][4][64]
    const __hip_bfloat16* __restrict__ Vt,  // [8][4][64][1024]
    __hip_bfloat16* __restrict__ Y)         // [N][16][64]
{
  __shared__ __align__(16) unsigned short Kb[2][4096];   // [buf][kc*2048 + key*32 + d]
  __shared__ __align__(16) unsigned short Vb[2][4096];   // [buf][kc*2048 + d*32 + key]
  __shared__ __align__(16) unsigned short Pm[4][32 * 72];

  const int p = blockIdx.x;           // 0..7
  const int qt_a = 15 - p, qt_b = p;  // paired: (16-p)+(p+1)=17 units, uniform
  const int kvh2 = blockIdx.y;        // 0..7
  const int kvh = kvh2 >> 1, hh = kvh2 & 1;
  const int b = blockIdx.z;
  const int tid = threadIdx.x;
  const int wave = tid >> 6, lane = tid & 63;
  const int quad = lane >> 4, l15 = lane & 15;
  const int h = kvh * 4 + hh * 2 + (wave >> 1);
  const int m0 = (wave & 1) * 32;
  const int srow = lane >> 2, scol = (lane & 3) * 8;

  auto issue = [&](int kt, unsigned short* Ks, unsigned short* Vs) {
#pragma unroll
    for (int c = 0; c < 4; c++) {
      const int ch = wave * 4 + c;          // 0..15: 8 K chunks + 8 V chunks
      const int v = ch >> 3;
      const int ch8 = ch & 7;
      const int kc = ch8 >> 2, grp = ch8 & 3;
      if (v == 0)
        async16(Kk + (size_t)(b * 1024 + kt * 64 + grp * 16 + srow) * 256 + kvh * 64 + kc * 32 + scol,
                Ks + kc * 2048 + grp * 512 + lane * 8);
      else
        async16(Vt + ((size_t)((b * 4 + kvh) * 64 + grp * 16 + srow)) * 1024 + kt * 64 + kc * 32 + scol,
                Vs + kc * 2048 + grp * 512 + lane * 8);
    }
  };

  // Q fragments for phase A (phase B reloads at the seam)
  bf16x8 qf[2][2];
  {
    const int tok0 = b * 1024 + qt_a * 64;
#pragma unroll
    for (int mt = 0; mt < 2; mt++)
#pragma unroll
      for (int kc = 0; kc < 2; kc++)
        qf[mt][kc] = *(const bf16x8*)(Q + (size_t)(tok0 + m0 + mt * 16 + l15) * 1024 +
                                      h * 64 + kc * 32 + quad * 8);
  }

  issue(0, Kb[0], Vb[0]);

  f32x4 of[2][4] = {};
  f32x4 lf[2] = {};
  unsigned short* Pw = Pm[wave];

  bf16x8 onesf;
#pragma unroll
  for (int j = 0; j < 8; j++) onesf[j] = (__bf16)1.0f;

  const int steps_a = qt_a + 1;
  const int total = steps_a + qt_b + 1;   // always 17

  for (int g = 0; g < total; ++g) {
    const bool pa = g < steps_a;
    const int qtc = pa ? qt_a : qt_b;
    const int kt = pa ? g : g - steps_a;

    __syncthreads();
    if (g + 1 < total) {
      const int gn = g + 1;
      const int ktn = (gn < steps_a) ? gn : gn - steps_a;
      issue(ktn, Kb[gn & 1], Vb[gn & 1]);
    }
    if (g == steps_a) {  // phase seam: load phase-B Q fragments
      const int tok0 = b * 1024 + qt_b * 64;
#pragma unroll
      for (int mt = 0; mt < 2; mt++)
#pragma unroll
        for (int kc = 0; kc < 2; kc++)
          qf[mt][kc] = *(const bf16x8*)(Q + (size_t)(tok0 + m0 + mt * 16 + l15) * 1024 +
                                        h * 64 + kc * 32 + quad * 8);
    }
    const unsigned short* Ks = Kb[g & 1];
    const unsigned short* Vs = Vb[g & 1];

    f32x4 sf[4][2] = {};
    __builtin_amdgcn_s_setprio(1);
#pragma unroll
    for (int kc = 0; kc < 2; kc++) {
#pragma unroll
      for (int kk = 0; kk < 4; kk++) {
        const bf16x8 kf = *(const bf16x8*)&Ks[kc * 2048 + (kk * 16 + l15) * 32 + quad * 8];
#pragma unroll
        for (int mt = 0; mt < 2; mt++)
          sf[kk][mt] = __builtin_amdgcn_mfma_f32_16x16x32_bf16(kf, qf[mt][kc], sf[kk][mt], 0, 0, 0);
      }
    }
    __builtin_amdgcn_s_setprio(0);

    const bool diag = (kt == qtc);
#pragma unroll
    for (int mt = 0; mt < 2; mt++) {
#pragma unroll
      for (int kk = 0; kk < 4; kk++) {
        ushort4 pk;
        unsigned short* pp = (unsigned short*)&pk;
#pragma unroll
        for (int r = 0; r < 4; r++) {
          float pv;
          if (diag && (kk * 16 + quad * 4 + r) > (m0 + mt * 16 + l15))
            pv = 0.0f;
          else
            pv = __builtin_amdgcn_exp2f(sf[kk][mt][r]);   // scale pre-folded into Q
          pp[r] = f2bfu(pv);
        }
        *(ushort4*)&Pw[(mt * 16 + l15) * 72 + kk * 16 + quad * 4] = pk;
      }
    }

    asm volatile("s_waitcnt lgkmcnt(0)" ::: "memory");

    __builtin_amdgcn_s_setprio(1);
#pragma unroll
    for (int kc = 0; kc < 2; kc++) {
#pragma unroll
      for (int mt = 0; mt < 2; mt++) {
        const bf16x8 ap = *(const bf16x8*)&Pw[(mt * 16 + l15) * 72 + kc * 32 + quad * 8];
        lf[mt] = __builtin_amdgcn_mfma_f32_16x16x32_bf16(ap, onesf, lf[mt], 0, 0, 0);
#pragma unroll
        for (int dt = 0; dt < 4; dt++) {
          const bf16x8 bv = *(const bf16x8*)&Vs[kc * 2048 + (dt * 16 + l15) * 32 + quad * 8];
          of[mt][dt] = __builtin_amdgcn_mfma_f32_16x16x32_bf16(ap, bv, of[mt][dt], 0, 0, 0);
        }
      }
    }
    __builtin_amdgcn_s_setprio(0);

    if (diag) {  // phase end: normalize + store, then reset accumulators
      const int tok0 = b * 1024 + qtc * 64;
#pragma unroll
      for (int mt = 0; mt < 2; mt++)
#pragma unroll
        for (int r = 0; r < 4; r++) {
          const float rcp = 1.0f / lf[mt][r];
          const int row = tok0 + m0 + mt * 16 + quad * 4 + r;
#pragma unroll
          for (int dt = 0; dt < 4; dt++)
            Y[(size_t)row * 1024 + h * 64 + dt * 16 + l15] = __float2bfloat16(of[mt][dt][r] * rcp);
        }
      if (pa) {
#pragma unroll
        for (int mt = 0; mt < 2; mt++) {
          lf[mt] = f32x4{0.f, 0.f, 0.f, 0.f};
#pragma unroll
          for (int dt = 0; dt < 4; dt++) of[mt][dt] = f32x4{0.f, 0.f, 0.f, 0.f};
        }
      }
    }
  }
}

// ---------------- launch ----------------
extern "C" void kernel_launch(void* const* d_in, const int* in_sizes, int n_in,
                              void* d_out, int out_size, void* d_ws, size_t ws_size,
                              hipStream_t stream) {
  const float* x      = (const float*)d_in[0];
  const float* Wq     = (const float*)d_in[1];
  const float* Wk     = (const float*)d_in[2];
  const float* Wv     = (const float*)d_in[3];
  const float* Wp     = (const float*)d_in[4];
  const float* qgain  = (const float*)d_in[5];
  const float* qscale = (const float*)d_in[6];
  const float* kscale = (const float*)d_in[7];
  const float* cosb   = (const float*)d_in[8];
  const float* sinb   = (const float*)d_in[9];
  float* out = (float*)d_out;
  char* ws = (char*)d_ws;

  __hip_bfloat16* xb  = (__hip_bfloat16*)(ws);                 // 8192x1024 bf16 @0
  __hip_bfloat16* w1b = (__hip_bfloat16*)(ws + 16777216);      // 1536x1024 bf16
  __hip_bfloat16* wpb = (__hip_bfloat16*)(ws + 19922944);      // 1024x1024 bf16
  __hip_bfloat16* qb  = (__hip_bfloat16*)(ws + 22020096);      // 8192x1024 bf16
  __hip_bfloat16* kb  = (__hip_bfloat16*)(ws + 38797312);      // 8192x256 bf16
  __hip_bfloat16* vkb = (__hip_bfloat16*)(ws + 42991616);      // 8192x256 bf16
  __hip_bfloat16* vtb = (__hip_bfloat16*)(ws + 47185920);      // 8x4x64x1024 bf16
  __hip_bfloat16* yb  = (__hip_bfloat16*)(ws + 51380224);      // 8192x1024 bf16

  castall<<<10752, 256, 0, stream>>>((const float4*)x, (const float4*)Wq, (const float4*)Wk,
                                     (const float4*)Wv, (const float4*)Wp,
                                     (ushort4*)xb, (ushort4*)w1b, (ushort4*)wpb);

  gemm_qkv<<<768, 256, 0, stream>>>(xb, w1b, cosb, sinb, qgain, qscale, kscale,
                                    qb, kb, vkb);

  vtrans<<<dim3(16, 4, 8), 256, 0, stream>>>((const unsigned short*)vkb, (unsigned short*)vtb);

  attn<<<dim3(8, 8, 8), 256, 0, stream>>>(qb, kb, vtb, yb);

  gemm_p<<<512, 256, 0, stream>>>(yb, wpb, out);
}

// Round 4
// 191.130 us; speedup vs baseline: 1.0994x; 1.0994x over previous
//
#include <hip/hip_runtime.h>
#include <hip/hip_bf16.h>

// ---- constants for this problem ----
// N=8192 tokens, DIM=1024, H=16, HKV=4, HD=64, B=8, S=1024

typedef __bf16 bf16x8 __attribute__((ext_vector_type(8)));
typedef float f32x4 __attribute__((ext_vector_type(4)));

__device__ __forceinline__ void async16(const void* g, void* l) {
  __builtin_amdgcn_global_load_lds((const __attribute__((address_space(1))) void*)g,
                                   (__attribute__((address_space(3))) void*)l, 16, 0, 0);
}

__device__ __forceinline__ unsigned short f2bfu(float x) {
  __hip_bfloat16 h = __float2bfloat16(x);
  return __builtin_bit_cast(unsigned short, h);
}

// ---------------- all input casts in one kernel ----------------
// regions (float4 units): x 2097152 | Wq 262144 | Wk 65536 | Wv 65536 | Wp 262144
__global__ __launch_bounds__(256) void castall(
    const float4* __restrict__ x, const float4* __restrict__ Wq,
    const float4* __restrict__ Wk, const float4* __restrict__ Wv,
    const float4* __restrict__ Wp,
    ushort4* __restrict__ xb, ushort4* __restrict__ w1b, ushort4* __restrict__ wpb) {
  int i = blockIdx.x * 256 + threadIdx.x;  // total 2752512
  const float4* src;
  ushort4* dst;
  if (i < 2097152)      { src = x + i;             dst = xb + i; }
  else if (i < 2359296) { src = Wq + (i - 2097152); dst = w1b + (i - 2097152); }
  else if (i < 2424832) { src = Wk + (i - 2359296); dst = w1b + (i - 2097152); }
  else if (i < 2490368) { src = Wv + (i - 2424832); dst = w1b + (i - 2097152); }
  else                  { src = Wp + (i - 2490368); dst = wpb + (i - 2490368); }
  float4 v = *src;
  ushort4 o;
  o.x = f2bfu(v.x); o.y = f2bfu(v.y); o.z = f2bfu(v.z); o.w = f2bfu(v.w);
  *dst = o;
}

// ---------------- fused QKV GEMM + RMSNorm + RoPE + gain -> bf16 q/k/vt ----------------
// v4: REVERT to round-2 structure (BK=64, single-buffered 32KB LDS, 2 barriers/iter
// — measured best; round-3's 64KB dbuf cut occupancy 3->2 blk/CU and regressed
// 44->49us). launch_bounds (256,4): LDS 32KB allows 4 blk/CU, VGPR fits 128 cap.
// NEW: V transpose fused into the V-head epilogue (wave holds the full 64tok x 64d
// tile in regs; each d-row stores one full 128B line since s0 is 64-aligned) —
// the separate vtrans kernel and the vkb intermediate are gone.
// Keeps: T2 XOR swizzle (pre-swizzled global source + swizzled read, rule #21),
// T1 bijective XCD remap, Q pre-scale by 0.125*log2e (softmax fold).
__global__ __launch_bounds__(256, 4) void gemm_qkv(
    const __hip_bfloat16* __restrict__ A,   // [8192][1024] bf16
    const __hip_bfloat16* __restrict__ Bm,  // [1536][1024] bf16
    const float* __restrict__ cosb, const float* __restrict__ sinb,
    const float* __restrict__ qgain, const float* __restrict__ qscale,
    const float* __restrict__ kscale,
    __hip_bfloat16* __restrict__ Qo,  // [8192][16][64]
    __hip_bfloat16* __restrict__ Ko,  // [8192][4][64]
    __hip_bfloat16* __restrict__ Vt)  // [8][4][64][1024]  (transposed V)
{
  __shared__ __align__(16) unsigned short As[128 * 64];
  __shared__ __align__(16) unsigned short Bs[128 * 64];
  const int tid = threadIdx.x;
  const int wave = tid >> 6, lane = tid & 63;
  const int quad = lane >> 4, l15 = lane & 15;
  // T1: bijective XCD swizzle (768 % 8 == 0)
  const int flat = blockIdx.x;
  const int swz = (flat & 7) * 96 + (flat >> 3);
  const int bn = swz % 12, bm = swz / 12;
  const int wm = (wave >> 1) * 64, wn = (wave & 1) * 64;
  // staging: chunk = 8 rows x 64 cols; dest LDS linear, source col pre-swizzled
  const int srow = lane >> 3;                    // row within chunk (== row&7)
  const int scol = ((lane & 7) ^ srow) * 8;      // inverse-swizzled global col
  const int K = 1024;

  f32x4 acc[4][4] = {};

  const __hip_bfloat16* Ab = A + (size_t)bm * 128 * K;
  const __hip_bfloat16* Bb = Bm + (size_t)bn * 128 * K;

  for (int kt = 0; kt < K; kt += 64) {
    __syncthreads();
#pragma unroll
    for (int c = 0; c < 4; c++) {
      const int ch = wave * 4 + c;               // 16 chunks cover 128 rows
      async16(Ab + (size_t)(ch * 8 + srow) * K + kt + scol, &As[ch * 512]);
      async16(Bb + (size_t)(ch * 8 + srow) * K + kt + scol, &Bs[ch * 512]);
    }
    __syncthreads();
#pragma unroll
    for (int ks = 0; ks < 2; ks++) {
      bf16x8 af[4], bfr[4];
#pragma unroll
      for (int mt = 0; mt < 4; mt++) {
        const int row = wm + mt * 16 + l15;
        af[mt] = *(const bf16x8*)&As[row * 64 + (((ks << 2) + quad) ^ (row & 7)) * 8];
      }
#pragma unroll
      for (int nt = 0; nt < 4; nt++) {
        const int row = wn + nt * 16 + l15;
        bfr[nt] = *(const bf16x8*)&Bs[row * 64 + (((ks << 2) + quad) ^ (row & 7)) * 8];
      }
#pragma unroll
      for (int mt = 0; mt < 4; mt++)
#pragma unroll
        for (int nt = 0; nt < 4; nt++)
          acc[mt][nt] = __builtin_amdgcn_mfma_f32_16x16x32_bf16(af[mt], bfr[nt], acc[mt][nt], 0, 0, 0);
    }
  }

  // ---- fused epilogue ----
  const int hg = bn * 2 + (wn >> 6);        // global output head 0..23
  const int tokbase = bm * 128 + wm;        // wave's first token

  if (hg >= 20) {
    // V head: store TRANSPOSED directly into Vt[b][kvh][d][s].
    // Each (d) row receives one full 128B line from this wave (s0 64-aligned).
    const int hv = hg - 20;
    const int bb = tokbase >> 10;
    const int s0 = tokbase & 1023;
    unsigned short* vt = (unsigned short*)Vt + ((size_t)(bb * 4 + hv) * 64) * 1024;
#pragma unroll
    for (int mt = 0; mt < 4; mt++)
#pragma unroll
      for (int r = 0; r < 4; r++) {
        const int so = s0 + mt * 16 + quad * 4 + r;
#pragma unroll
        for (int nt = 0; nt < 4; nt++)
          vt[(size_t)(nt * 16 + l15) * 1024 + so] = f2bfu(acc[mt][nt][r]);
      }
  } else {
    const bool isq = hg < 16;
    const float scale = isq ? qscale[0] : kscale[0];
    // rope/gain/softmax-scale are all linear -> fold gain AND 0.125*log2e into inv (Q only)
    const float gain = isq ? qgain[hg] * 0.18033688011112042f : 1.0f;
    const float sg = scale * gain;
#pragma unroll
    for (int mt = 0; mt < 4; mt++) {
      float inv[4];
#pragma unroll
      for (int r = 0; r < 4; r++) {
        float ss = acc[mt][0][r] * acc[mt][0][r] + acc[mt][1][r] * acc[mt][1][r] +
                   acc[mt][2][r] * acc[mt][2][r] + acc[mt][3][r] * acc[mt][3][r];
#pragma unroll
        for (int off = 1; off < 16; off <<= 1) ss += __shfl_xor(ss, off);
        inv[r] = rsqrtf(ss * (1.0f / 64.0f) + 1.1920929e-07f) * sg;
      }
#pragma unroll
      for (int r = 0; r < 4; r++) {
        const int tok = tokbase + mt * 16 + quad * 4 + r;
        const float c0 = cosb[tok * 32 + l15], c1 = cosb[tok * 32 + 16 + l15];
        const float s0 = sinb[tok * 32 + l15], s1 = sinb[tok * 32 + 16 + l15];
        const float v0 = acc[mt][0][r] * inv[r];
        const float v1 = acc[mt][1][r] * inv[r];
        const float v2 = acc[mt][2][r] * inv[r];
        const float v3 = acc[mt][3][r] * inv[r];
        const float o0 = v0 * c0 + v2 * s0;
        const float o1 = v1 * c1 + v3 * s1;
        const float o2 = -v0 * s0 + v2 * c0;
        const float o3 = -v1 * s1 + v3 * c1;
        __hip_bfloat16* base = isq ? (Qo + (size_t)tok * 1024 + hg * 64)
                                   : (Ko + (size_t)tok * 256 + (hg - 16) * 64);
        base[l15]      = __float2bfloat16(o0);
        base[16 + l15] = __float2bfloat16(o1);
        base[32 + l15] = __float2bfloat16(o2);
        base[48 + l15] = __float2bfloat16(o3);
      }
    }
  }
}

// ---------------- proj GEMM: out = y @ Wp^T, 128x128, BK=64 (round-2 structure) ----------------
__global__ __launch_bounds__(256, 4) void gemm_p(
    const __hip_bfloat16* __restrict__ A,   // [8192][1024] bf16
    const __hip_bfloat16* __restrict__ Bm,  // [1024][1024] bf16
    float* __restrict__ C)                  // [8192][1024] f32
{
  __shared__ __align__(16) unsigned short As[128 * 64];
  __shared__ __align__(16) unsigned short Bs[128 * 64];
  const int tid = threadIdx.x;
  const int wave = tid >> 6, lane = tid & 63;
  const int quad = lane >> 4, l15 = lane & 15;
  // T1: bijective XCD swizzle (512 % 8 == 0)
  const int flat = blockIdx.x;
  const int swz = (flat & 7) * 64 + (flat >> 3);
  const int bn = swz & 7, bm = swz >> 3;
  const int wm = (wave >> 1) * 64, wn = (wave & 1) * 64;
  const int srow = lane >> 3;
  const int scol = ((lane & 7) ^ srow) * 8;
  const int K = 1024;

  f32x4 acc[4][4] = {};

  const __hip_bfloat16* Ab = A + (size_t)bm * 128 * K;
  const __hip_bfloat16* Bb = Bm + (size_t)bn * 128 * K;

  for (int kt = 0; kt < K; kt += 64) {
    __syncthreads();
#pragma unroll
    for (int c = 0; c < 4; c++) {
      const int ch = wave * 4 + c;
      async16(Ab + (size_t)(ch * 8 + srow) * K + kt + scol, &As[ch * 512]);
      async16(Bb + (size_t)(ch * 8 + srow) * K + kt + scol, &Bs[ch * 512]);
    }
    __syncthreads();
#pragma unroll
    for (int ks = 0; ks < 2; ks++) {
      bf16x8 af[4], bfr[4];
#pragma unroll
      for (int mt = 0; mt < 4; mt++) {
        const int row = wm + mt * 16 + l15;
        af[mt] = *(const bf16x8*)&As[row * 64 + (((ks << 2) + quad) ^ (row & 7)) * 8];
      }
#pragma unroll
      for (int nt = 0; nt < 4; nt++) {
        const int row = wn + nt * 16 + l15;
        bfr[nt] = *(const bf16x8*)&Bs[row * 64 + (((ks << 2) + quad) ^ (row & 7)) * 8];
      }
#pragma unroll
      for (int mt = 0; mt < 4; mt++)
#pragma unroll
        for (int nt = 0; nt < 4; nt++)
          acc[mt][nt] = __builtin_amdgcn_mfma_f32_16x16x32_bf16(af[mt], bfr[nt], acc[mt][nt], 0, 0, 0);
    }
  }

#pragma unroll
  for (int mt = 0; mt < 4; mt++)
#pragma unroll
    for (int r = 0; r < 4; r++) {
      const int row = bm * 128 + wm + mt * 16 + quad * 4 + r;
#pragma unroll
      for (int nt = 0; nt < 4; nt++)
        C[(size_t)row * 1024 + bn * 128 + wn + nt * 16 + l15] = acc[mt][nt][r];
    }
}

// ---------------- flash attention v4 (unchanged) ----------------
__global__ __launch_bounds__(256, 2) void attn(
    const __hip_bfloat16* __restrict__ Q,   // [N][16][64] (pre-scaled)
    const __hip_bfloat16* __restrict__ Kk,  // [N][4][64]
    const __hip_bfloat16* __restrict__ Vt,  // [8][4][64][1024]
    __hip_bfloat16* __restrict__ Y)         // [N][16][64]
{
  __shared__ __align__(16) unsigned short Kb[2][4096];   // [buf][kc*2048 + key*32 + d]
  __shared__ __align__(16) unsigned short Vb[2][4096];   // [buf][kc*2048 + d*32 + key]
  __shared__ __align__(16) unsigned short Pm[4][32 * 72];

  const int p = blockIdx.x;           // 0..7
  const int qt_a = 15 - p, qt_b = p;  // paired: (16-p)+(p+1)=17 units, uniform
  const int kvh2 = blockIdx.y;        // 0..7
  const int kvh = kvh2 >> 1, hh = kvh2 & 1;
  const int b = blockIdx.z;
  const int tid = threadIdx.x;
  const int wave = tid >> 6, lane = tid & 63;
  const int quad = lane >> 4, l15 = lane & 15;
  const int h = kvh * 4 + hh * 2 + (wave >> 1);
  const int m0 = (wave & 1) * 32;
  const int srow = lane >> 2, scol = (lane & 3) * 8;

  auto issue = [&](int kt, unsigned short* Ks, unsigned short* Vs) {
#pragma unroll
    for (int c = 0; c < 4; c++) {
      const int ch = wave * 4 + c;          // 0..15: 8 K chunks + 8 V chunks
      const int v = ch >> 3;
      const int ch8 = ch & 7;
      const int kc = ch8 >> 2, grp = ch8 & 3;
      if (v == 0)
        async16(Kk + (size_t)(b * 1024 + kt * 64 + grp * 16 + srow) * 256 + kvh * 64 + kc * 32 + scol,
                Ks + kc * 2048 + grp * 512 + lane * 8);
      else
        async16(Vt + ((size_t)((b * 4 + kvh) * 64 + grp * 16 + srow)) * 1024 + kt * 64 + kc * 32 + scol,
                Vs + kc * 2048 + grp * 512 + lane * 8);
    }
  };

  // Q fragments for phase A (phase B reloads at the seam)
  bf16x8 qf[2][2];
  {
    const int tok0 = b * 1024 + qt_a * 64;
#pragma unroll
    for (int mt = 0; mt < 2; mt++)
#pragma unroll
      for (int kc = 0; kc < 2; kc++)
        qf[mt][kc] = *(const bf16x8*)(Q + (size_t)(tok0 + m0 + mt * 16 + l15) * 1024 +
                                      h * 64 + kc * 32 + quad * 8);
  }

  issue(0, Kb[0], Vb[0]);

  f32x4 of[2][4] = {};
  f32x4 lf[2] = {};
  unsigned short* Pw = Pm[wave];

  bf16x8 onesf;
#pragma unroll
  for (int j = 0; j < 8; j++) onesf[j] = (__bf16)1.0f;

  const int steps_a = qt_a + 1;
  const int total = steps_a + qt_b + 1;   // always 17

  for (int g = 0; g < total; ++g) {
    const bool pa = g < steps_a;
    const int qtc = pa ? qt_a : qt_b;
    const int kt = pa ? g : g - steps_a;

    __syncthreads();
    if (g + 1 < total) {
      const int gn = g + 1;
      const int ktn = (gn < steps_a) ? gn : gn - steps_a;
      issue(ktn, Kb[gn & 1], Vb[gn & 1]);
    }
    if (g == steps_a) {  // phase seam: load phase-B Q fragments
      const int tok0 = b * 1024 + qt_b * 64;
#pragma unroll
      for (int mt = 0; mt < 2; mt++)
#pragma unroll
        for (int kc = 0; kc < 2; kc++)
          qf[mt][kc] = *(const bf16x8*)(Q + (size_t)(tok0 + m0 + mt * 16 + l15) * 1024 +
                                        h * 64 + kc * 32 + quad * 8);
    }
    const unsigned short* Ks = Kb[g & 1];
    const unsigned short* Vs = Vb[g & 1];

    f32x4 sf[4][2] = {};
    __builtin_amdgcn_s_setprio(1);
#pragma unroll
    for (int kc = 0; kc < 2; kc++) {
#pragma unroll
      for (int kk = 0; kk < 4; kk++) {
        const bf16x8 kf = *(const bf16x8*)&Ks[kc * 2048 + (kk * 16 + l15) * 32 + quad * 8];
#pragma unroll
        for (int mt = 0; mt < 2; mt++)
          sf[kk][mt] = __builtin_amdgcn_mfma_f32_16x16x32_bf16(kf, qf[mt][kc], sf[kk][mt], 0, 0, 0);
      }
    }
    __builtin_amdgcn_s_setprio(0);

    const bool diag = (kt == qtc);
#pragma unroll
    for (int mt = 0; mt < 2; mt++) {
#pragma unroll
      for (int kk = 0; kk < 4; kk++) {
        ushort4 pk;
        unsigned short* pp = (unsigned short*)&pk;
#pragma unroll
        for (int r = 0; r < 4; r++) {
          float pv;
          if (diag && (kk * 16 + quad * 4 + r) > (m0 + mt * 16 + l15))
            pv = 0.0f;
          else
            pv = __builtin_amdgcn_exp2f(sf[kk][mt][r]);   // scale pre-folded into Q
          pp[r] = f2bfu(pv);
        }
        *(ushort4*)&Pw[(mt * 16 + l15) * 72 + kk * 16 + quad * 4] = pk;
      }
    }

    asm volatile("s_waitcnt lgkmcnt(0)" ::: "memory");

    __builtin_amdgcn_s_setprio(1);
#pragma unroll
    for (int kc = 0; kc < 2; kc++) {
#pragma unroll
      for (int mt = 0; mt < 2; mt++) {
        const bf16x8 ap = *(const bf16x8*)&Pw[(mt * 16 + l15) * 72 + kc * 32 + quad * 8];
        lf[mt] = __builtin_amdgcn_mfma_f32_16x16x32_bf16(ap, onesf, lf[mt], 0, 0, 0);
#pragma unroll
        for (int dt = 0; dt < 4; dt++) {
          const bf16x8 bv = *(const bf16x8*)&Vs[kc * 2048 + (dt * 16 + l15) * 32 + quad * 8];
          of[mt][dt] = __builtin_amdgcn_mfma_f32_16x16x32_bf16(ap, bv, of[mt][dt], 0, 0, 0);
        }
      }
    }
    __builtin_amdgcn_s_setprio(0);

    if (diag) {  // phase end: normalize + store, then reset accumulators
      const int tok0 = b * 1024 + qtc * 64;
#pragma unroll
      for (int mt = 0; mt < 2; mt++)
#pragma unroll
        for (int r = 0; r < 4; r++) {
          const float rcp = 1.0f / lf[mt][r];
          const int row = tok0 + m0 + mt * 16 + quad * 4 + r;
#pragma unroll
          for (int dt = 0; dt < 4; dt++)
            Y[(size_t)row * 1024 + h * 64 + dt * 16 + l15] = __float2bfloat16(of[mt][dt][r] * rcp);
        }
      if (pa) {
#pragma unroll
        for (int mt = 0; mt < 2; mt++) {
          lf[mt] = f32x4{0.f, 0.f, 0.f, 0.f};
#pragma unroll
          for (int dt = 0; dt < 4; dt++) of[mt][dt] = f32x4{0.f, 0.f, 0.f, 0.f};
        }
      }
    }
  }
}

// ---------------- launch ----------------
extern "C" void kernel_launch(void* const* d_in, const int* in_sizes, int n_in,
                              void* d_out, int out_size, void* d_ws, size_t ws_size,
                              hipStream_t stream) {
  const float* x      = (const float*)d_in[0];
  const float* Wq     = (const float*)d_in[1];
  const float* Wk     = (const float*)d_in[2];
  const float* Wv     = (const float*)d_in[3];
  const float* Wp     = (const float*)d_in[4];
  const float* qgain  = (const float*)d_in[5];
  const float* qscale = (const float*)d_in[6];
  const float* kscale = (const float*)d_in[7];
  const float* cosb   = (const float*)d_in[8];
  const float* sinb   = (const float*)d_in[9];
  float* out = (float*)d_out;
  char* ws = (char*)d_ws;

  __hip_bfloat16* xb  = (__hip_bfloat16*)(ws);                 // 8192x1024 bf16 @0
  __hip_bfloat16* w1b = (__hip_bfloat16*)(ws + 16777216);      // 1536x1024 bf16
  __hip_bfloat16* wpb = (__hip_bfloat16*)(ws + 19922944);      // 1024x1024 bf16
  __hip_bfloat16* qb  = (__hip_bfloat16*)(ws + 22020096);      // 8192x1024 bf16
  __hip_bfloat16* kb  = (__hip_bfloat16*)(ws + 38797312);      // 8192x256 bf16
  __hip_bfloat16* vtb = (__hip_bfloat16*)(ws + 47185920);      // 8x4x64x1024 bf16
  __hip_bfloat16* yb  = (__hip_bfloat16*)(ws + 51380224);      // 8192x1024 bf16

  castall<<<10752, 256, 0, stream>>>((const float4*)x, (const float4*)Wq, (const float4*)Wk,
                                     (const float4*)Wv, (const float4*)Wp,
                                     (ushort4*)xb, (ushort4*)w1b, (ushort4*)wpb);

  gemm_qkv<<<768, 256, 0, stream>>>(xb, w1b, cosb, sinb, qgain, qscale, kscale,
                                    qb, kb, vtb);

  attn<<<dim3(8, 8, 8), 256, 0, stream>>>(qb, kb, vtb, yb);

  gemm_p<<<512, 256, 0, stream>>>(yb, wpb, out);
}